// Round 1
// baseline (811.827 us; speedup 1.0000x reference)
//
#include <hip/hip_runtime.h>
#include <stdint.h>
#include <math.h>

// Problem constants (B=2,S=2048,H=1024,E=8,K=2,F=4096)
#define T_TOK 4096
#define H_DIM 1024
#define E_EXP 8
#define F_DIM 4096
#define NASSIGN (T_TOK * 2)
#define OUT_ELEMS ((size_t)T_TOK * H_DIM)

typedef unsigned short u16;
typedef __attribute__((ext_vector_type(8))) short short8;   // 8 bf16 = 4 VGPRs
typedef __attribute__((ext_vector_type(4))) float f32x4;

__device__ __forceinline__ u16 f2bf(float f) {
  union { float f; uint32_t u; } c; c.f = f;
  uint32_t u = c.u;
  return (u16)((u + 0x7FFFu + ((u >> 16) & 1u)) >> 16);  // RNE
}

// async global->LDS, 16B per lane. LDS dest must be wave-uniform base + lane*16.
__device__ __forceinline__ void gl_lds16(const void* g, void* l) {
  __builtin_amdgcn_global_load_lds(
      (const __attribute__((address_space(1))) uint32_t*)g,
      (__attribute__((address_space(3))) uint32_t*)(uintptr_t)l, 16, 0, 0);
}

// ---------------- conversion kernels ----------------

__global__ void cvt_x_kernel(const float* __restrict__ x, u16* __restrict__ xb) {
  const size_t i = ((size_t)blockIdx.x * 256 + threadIdx.x) * 8;
  const float4 u = *(const float4*)(x + i);
  const float4 v = *(const float4*)(x + i + 4);
  short8 o;
  o[0] = (short)f2bf(u.x); o[1] = (short)f2bf(u.y);
  o[2] = (short)f2bf(u.z); o[3] = (short)f2bf(u.w);
  o[4] = (short)f2bf(v.x); o[5] = (short)f2bf(v.y);
  o[6] = (short)f2bf(v.z); o[7] = (short)f2bf(v.w);
  *(short8*)(xb + i) = o;
}

// in: [E][R][C] fp32  ->  out: [E][C][R] bf16   (64x64 tiles via LDS)
__global__ void transpose_cvt_kernel(const float* __restrict__ in,
                                     u16* __restrict__ out, int R, int C) {
  __shared__ float tile[64][65];
  const int tx = threadIdx.x & 63;
  const int ty = threadIdx.x >> 6;  // 0..3
  const int c0 = blockIdx.x * 64;
  const int r0 = blockIdx.y * 64;
  const size_t eoff = (size_t)blockIdx.z * R * C;
  const float* inp = in + eoff + (size_t)r0 * C + c0;
#pragma unroll
  for (int rr = ty; rr < 64; rr += 4) tile[rr][tx] = inp[(size_t)rr * C + tx];
  __syncthreads();
  u16* op = out + eoff + (size_t)c0 * R + r0;
#pragma unroll
  for (int cc = ty; cc < 64; cc += 4) op[(size_t)cc * R + tx] = f2bf(tile[tx][cc]);
}

// ---------------- router ----------------
// one wave per token: logits = x@Wr + br, softmax, top-2, renorm, counts, lse
__global__ void router_kernel(const float* __restrict__ x, const float* __restrict__ Wr,
                              const float* __restrict__ br, int* __restrict__ tki,
                              float* __restrict__ tkw, int* __restrict__ counts,
                              float* __restrict__ zsum) {
  const int wave = threadIdx.x >> 6;
  const int lane = threadIdx.x & 63;
  const int t = blockIdx.x * 4 + wave;
  const float* xr = x + (size_t)t * H_DIM;
  float acc[8];
#pragma unroll
  for (int e = 0; e < 8; ++e) acc[e] = 0.0f;
#pragma unroll
  for (int j = 0; j < 16; ++j) {
    const int hh = j * 64 + lane;
    const float xv = xr[hh];
    const float4 w0 = *(const float4*)(Wr + (size_t)hh * 8);
    const float4 w1 = *(const float4*)(Wr + (size_t)hh * 8 + 4);
    acc[0] += xv * w0.x; acc[1] += xv * w0.y; acc[2] += xv * w0.z; acc[3] += xv * w0.w;
    acc[4] += xv * w1.x; acc[5] += xv * w1.y; acc[6] += xv * w1.z; acc[7] += xv * w1.w;
  }
#pragma unroll
  for (int e = 0; e < 8; ++e) {
    float v = acc[e];
#pragma unroll
    for (int s = 32; s > 0; s >>= 1) v += __shfl_xor(v, s);
    acc[e] = v;
  }
  if (lane == 0) {
    float l[8];
#pragma unroll
    for (int e = 0; e < 8; ++e) l[e] = acc[e] + br[e];
    float mx = l[0];
#pragma unroll
    for (int e = 1; e < 8; ++e) mx = fmaxf(mx, l[e]);
    float p[8], s = 0.0f;
#pragma unroll
    for (int e = 0; e < 8; ++e) { p[e] = __expf(l[e] - mx); s += p[e]; }
    int i0 = 0;
#pragma unroll
    for (int e = 1; e < 8; ++e) if (p[e] > p[i0]) i0 = e;
    int i1 = (i0 == 0) ? 1 : 0;
#pragma unroll
    for (int e = 0; e < 8; ++e) if (e != i1 && e != i0 && p[e] > p[i1]) i1 = e;
    const float ws = p[i0] + p[i1];
    tki[2 * t] = i0; tki[2 * t + 1] = i1;
    tkw[2 * t] = p[i0] / ws; tkw[2 * t + 1] = p[i1] / ws;
    atomicAdd(&counts[i0], 1);
    atomicAdd(&counts[i1], 1);
    atomicAdd(zsum, mx + logf(s));
  }
}

__global__ void prefix_kernel(const int* __restrict__ counts, int* __restrict__ offs) {
  if (threadIdx.x == 0) {
    int a = 0;
#pragma unroll
    for (int e = 0; e < 8; ++e) { offs[e] = a; a += counts[e]; }
  }
}

__global__ void scatter_kernel(const int* __restrict__ tki, const float* __restrict__ tkw,
                               const int* __restrict__ offs, int* __restrict__ cursor,
                               int* __restrict__ perm, float* __restrict__ pw) {
  const int t = blockIdx.x * 256 + threadIdx.x;
#pragma unroll
  for (int k = 0; k < 2; ++k) {
    const int e = tki[2 * t + k];
    const int p = atomicAdd(&cursor[e], 1);
    perm[offs[e] + p] = t;
    pw[offs[e] + p] = tkw[2 * t + k];
  }
}

// ---------------- grouped GEMMs (m97 structure: 128x128 tile, BK=32) ----------------

// h[slot][F] = gelu( xb[perm[slot]] @ W1t[e]^T + b1[e] )  (bf16 out)
__global__ __launch_bounds__(256, 2) void gemm1_kernel(
    const u16* __restrict__ xb, const u16* __restrict__ w1t,
    const float* __restrict__ b1, const int* __restrict__ perm,
    const int* __restrict__ cnts, const int* __restrict__ offs,
    u16* __restrict__ hbuf) {
  const int e = blockIdx.z;
  const int cnt = cnts[e];
  const int m0 = blockIdx.y * 128;
  if (m0 >= cnt) return;
  const int off = offs[e];
  const int n0 = blockIdx.x * 128;

  __shared__ __align__(16) u16 As[128 * 32];
  __shared__ __align__(16) u16 Bs[128 * 32];

  const int tid = threadIdx.x;
  const int r = tid >> 2;
  const int kc = (tid & 3) * 8;

  int ra0 = m0 + r;       if (ra0 > cnt - 1) ra0 = cnt - 1;
  int ra1 = m0 + r + 64;  if (ra1 > cnt - 1) ra1 = cnt - 1;
  const int tok0 = perm[off + ra0];
  const int tok1 = perm[off + ra1];
  const u16* ap0 = xb + (size_t)tok0 * H_DIM + kc;
  const u16* ap1 = xb + (size_t)tok1 * H_DIM + kc;
  const u16* bp0 = w1t + ((size_t)e * F_DIM + n0 + r) * H_DIM + kc;
  const u16* bp1 = bp0 + (size_t)64 * H_DIM;

  const int wave = tid >> 6;
  const int lane = tid & 63;
  const int wm = (wave >> 1) * 64;
  const int wn = (wave & 1) * 64;
  const int lr = lane & 15;
  const int q = lane >> 4;

  f32x4 acc[4][4];
#pragma unroll
  for (int i = 0; i < 4; ++i)
#pragma unroll
    for (int j = 0; j < 4; ++j) acc[i][j] = (f32x4)0.0f;

  const short8* Afr = (const short8*)As;
  const short8* Bfr = (const short8*)Bs;
  const int a_base = (wm + lr) * 4 + q;  // short8 units: row*4 + q
  const int b_base = (wn + lr) * 4 + q;

  for (int k0 = 0; k0 < H_DIM; k0 += 32) {
    gl_lds16(ap0, &As[tid * 8]);
    gl_lds16(ap1, &As[(tid + 256) * 8]);
    gl_lds16(bp0, &Bs[tid * 8]);
    gl_lds16(bp1, &Bs[(tid + 256) * 8]);
    ap0 += 32; ap1 += 32; bp0 += 32; bp1 += 32;
    __syncthreads();
    short8 a[4], b[4];
#pragma unroll
    for (int i = 0; i < 4; ++i) a[i] = Afr[a_base + i * 64];
#pragma unroll
    for (int j = 0; j < 4; ++j) b[j] = Bfr[b_base + j * 64];
#pragma unroll
    for (int i = 0; i < 4; ++i)
#pragma unroll
      for (int j = 0; j < 4; ++j)
        acc[i][j] = __builtin_amdgcn_mfma_f32_16x16x32_bf16(a[i], b[j], acc[i][j], 0, 0, 0);
    __syncthreads();
  }

#pragma unroll
  for (int i = 0; i < 4; ++i) {
#pragma unroll
    for (int rr = 0; rr < 4; ++rr) {
      const int m = m0 + wm + i * 16 + q * 4 + rr;
      if (m < cnt) {
        u16* hrow = hbuf + (size_t)(off + m) * F_DIM;
#pragma unroll
        for (int j = 0; j < 4; ++j) {
          const int col = n0 + wn + j * 16 + lr;
          const float v = acc[i][j][rr] + b1[e * F_DIM + col];
          const float g = 0.5f * v * (1.0f + erff(v * 0.70710678118654752f));
          hrow[col] = f2bf(g);
        }
      }
    }
  }
}

// out[token] += w * (h[slot] @ W2t[e]^T + b2[e])
__global__ __launch_bounds__(256, 2) void gemm2_kernel(
    const u16* __restrict__ hbuf, const u16* __restrict__ w2t,
    const float* __restrict__ b2, const int* __restrict__ perm,
    const float* __restrict__ pw, const int* __restrict__ cnts,
    const int* __restrict__ offs, float* __restrict__ out) {
  const int e = blockIdx.z;
  const int cnt = cnts[e];
  const int m0 = blockIdx.y * 128;
  if (m0 >= cnt) return;
  const int off = offs[e];
  const int n0 = blockIdx.x * 128;

  __shared__ __align__(16) u16 As[128 * 32];
  __shared__ __align__(16) u16 Bs[128 * 32];

  const int tid = threadIdx.x;
  const int r = tid >> 2;
  const int kc = (tid & 3) * 8;

  int ra0 = m0 + r;       if (ra0 > cnt - 1) ra0 = cnt - 1;
  int ra1 = m0 + r + 64;  if (ra1 > cnt - 1) ra1 = cnt - 1;
  const u16* ap0 = hbuf + (size_t)(off + ra0) * F_DIM + kc;
  const u16* ap1 = hbuf + (size_t)(off + ra1) * F_DIM + kc;
  const u16* bp0 = w2t + ((size_t)e * H_DIM + n0 + r) * F_DIM + kc;
  const u16* bp1 = bp0 + (size_t)64 * F_DIM;

  const int wave = tid >> 6;
  const int lane = tid & 63;
  const int wm = (wave >> 1) * 64;
  const int wn = (wave & 1) * 64;
  const int lr = lane & 15;
  const int q = lane >> 4;

  f32x4 acc[4][4];
#pragma unroll
  for (int i = 0; i < 4; ++i)
#pragma unroll
    for (int j = 0; j < 4; ++j) acc[i][j] = (f32x4)0.0f;

  const short8* Afr = (const short8*)As;
  const short8* Bfr = (const short8*)Bs;
  const int a_base = (wm + lr) * 4 + q;
  const int b_base = (wn + lr) * 4 + q;

  for (int k0 = 0; k0 < F_DIM; k0 += 32) {
    gl_lds16(ap0, &As[tid * 8]);
    gl_lds16(ap1, &As[(tid + 256) * 8]);
    gl_lds16(bp0, &Bs[tid * 8]);
    gl_lds16(bp1, &Bs[(tid + 256) * 8]);
    ap0 += 32; ap1 += 32; bp0 += 32; bp1 += 32;
    __syncthreads();
    short8 a[4], b[4];
#pragma unroll
    for (int i = 0; i < 4; ++i) a[i] = Afr[a_base + i * 64];
#pragma unroll
    for (int j = 0; j < 4; ++j) b[j] = Bfr[b_base + j * 64];
#pragma unroll
    for (int i = 0; i < 4; ++i)
#pragma unroll
      for (int j = 0; j < 4; ++j)
        acc[i][j] = __builtin_amdgcn_mfma_f32_16x16x32_bf16(a[i], b[j], acc[i][j], 0, 0, 0);
    __syncthreads();
  }

#pragma unroll
  for (int i = 0; i < 4; ++i) {
#pragma unroll
    for (int rr = 0; rr < 4; ++rr) {
      const int m = m0 + wm + i * 16 + q * 4 + rr;
      if (m < cnt) {
        const int slot = off + m;
        const int token = perm[slot];
        const float w = pw[slot];
        float* orow = out + (size_t)token * H_DIM;
#pragma unroll
        for (int j = 0; j < 4; ++j) {
          const int col = n0 + wn + j * 16 + lr;
          const float y = acc[i][j][rr] + b2[e * H_DIM + col];
          atomicAdd(&orow[col], w * y);
        }
      }
    }
  }
}

__global__ void loss_kernel(const int* __restrict__ counts, const float* __restrict__ zsum,
                            float* __restrict__ out_loss) {
  if (threadIdx.x == 0 && blockIdx.x == 0) {
    float aux = 0.0f;
#pragma unroll
    for (int e = 0; e < 8; ++e) {
      const float d = (float)counts[e] / (float)NASSIGN - 0.125f;
      aux += d * d;
    }
    aux *= (1.0f / 8.0f);
    const float z = zsum[0] / (float)T_TOK;
    out_loss[0] = 0.01f * aux + 0.001f * z;
  }
}

// ---------------- launch ----------------

extern "C" void kernel_launch(void* const* d_in, const int* in_sizes, int n_in,
                              void* d_out, int out_size, void* d_ws, size_t ws_size,
                              hipStream_t stream) {
  const float* x  = (const float*)d_in[0];
  const float* Wr = (const float*)d_in[1];
  const float* br = (const float*)d_in[2];
  const float* W1 = (const float*)d_in[3];
  const float* b1 = (const float*)d_in[4];
  const float* W2 = (const float*)d_in[5];
  const float* b2 = (const float*)d_in[6];
  float* out = (float*)d_out;

  // workspace layout (~210 MB)
  char* ws = (char*)d_ws;
  u16* xb    = (u16*)(ws);                          // 8 MB
  u16* w1t   = (u16*)(ws + 8388608ull);             // 64 MB  [E][F][H] bf16
  u16* w2t   = (u16*)(ws + 75497472ull);            // 64 MB  [E][H][F] bf16
  u16* hbuf  = (u16*)(ws + 142606336ull);           // 64 MB  [8192][F] bf16
  int*   tki    = (int*)(ws + 209715200ull);
  float* tkw    = (float*)(ws + 209747968ull);
  int*   perm   = (int*)(ws + 209780736ull);
  float* pw     = (float*)(ws + 209813504ull);
  int*   counts = (int*)(ws + 209846272ull);        // counts[8], offs[8], cursor[8], zsum
  int*   offs   = counts + 8;
  int*   cursor = counts + 16;
  float* zsum   = (float*)(counts + 24);

  hipMemsetAsync(out, 0, (size_t)out_size * sizeof(float), stream);
  hipMemsetAsync(counts, 0, 128, stream);

  cvt_x_kernel<<<2048, 256, 0, stream>>>(x, xb);
  // W1 [E][H][F] -> w1t [E][F][H]:  R=H, C=F
  transpose_cvt_kernel<<<dim3(F_DIM / 64, H_DIM / 64, E_EXP), 256, 0, stream>>>(W1, w1t, H_DIM, F_DIM);
  // W2 [E][F][H] -> w2t [E][H][F]:  R=F, C=H
  transpose_cvt_kernel<<<dim3(H_DIM / 64, F_DIM / 64, E_EXP), 256, 0, stream>>>(W2, w2t, F_DIM, H_DIM);
  router_kernel<<<T_TOK / 4, 256, 0, stream>>>(x, Wr, br, tki, tkw, counts, zsum);
  prefix_kernel<<<1, 64, 0, stream>>>(counts, offs);
  scatter_kernel<<<T_TOK / 256, 256, 0, stream>>>(tki, tkw, offs, cursor, perm, pw);
  gemm1_kernel<<<dim3(F_DIM / 128, T_TOK / 128, E_EXP), 256, 0, stream>>>(
      xb, w1t, b1, perm, counts, offs, hbuf);
  gemm2_kernel<<<dim3(H_DIM / 128, T_TOK / 128, E_EXP), 256, 0, stream>>>(
      hbuf, w2t, b2, perm, pw, counts, offs, out);
  loss_kernel<<<1, 64, 0, stream>>>(counts, zsum, out + OUT_ELEMS);
}

// Round 2
// 784.203 us; speedup vs baseline: 1.0352x; 1.0352x over previous
//
#include <hip/hip_runtime.h>
#include <stdint.h>
#include <math.h>

// Problem constants (B=2,S=2048,H=1024,E=8,K=2,F=4096)
#define T_TOK 4096
#define H_DIM 1024
#define E_EXP 8
#define F_DIM 4096
#define NASSIGN (T_TOK * 2)
#define OUT_ELEMS ((size_t)T_TOK * H_DIM)

typedef unsigned short u16;
typedef __attribute__((ext_vector_type(8))) short short8;   // 8 bf16 = 4 VGPRs
typedef __attribute__((ext_vector_type(4))) float f32x4;

__device__ __forceinline__ u16 f2bf(float f) {
  union { float f; uint32_t u; } c; c.f = f;
  uint32_t u = c.u;
  return (u16)((u + 0x7FFFu + ((u >> 16) & 1u)) >> 16);  // RNE
}

// async global->LDS, 16B per lane. LDS dest must be wave-uniform base + lane*16.
__device__ __forceinline__ void gl_lds16(const void* g, void* l) {
  __builtin_amdgcn_global_load_lds(
      (const __attribute__((address_space(1))) uint32_t*)g,
      (__attribute__((address_space(3))) uint32_t*)(uintptr_t)l, 16, 0, 0);
}

// ---------------- conversion kernels ----------------

__global__ void cvt_x_kernel(const float* __restrict__ x, u16* __restrict__ xb) {
  const size_t i = ((size_t)blockIdx.x * 256 + threadIdx.x) * 8;
  const float4 u = *(const float4*)(x + i);
  const float4 v = *(const float4*)(x + i + 4);
  short8 o;
  o[0] = (short)f2bf(u.x); o[1] = (short)f2bf(u.y);
  o[2] = (short)f2bf(u.z); o[3] = (short)f2bf(u.w);
  o[4] = (short)f2bf(v.x); o[5] = (short)f2bf(v.y);
  o[6] = (short)f2bf(v.z); o[7] = (short)f2bf(v.w);
  *(short8*)(xb + i) = o;
}

// in: [E][R][C] fp32  ->  out: [E][C][R] bf16   (64x64 tiles via LDS)
// float4 coalesced loads; short8 (16B) coalesced stores.
__global__ __launch_bounds__(256) void transpose_cvt_kernel(
    const float* __restrict__ in, u16* __restrict__ out, int R, int C) {
  __shared__ u16 tile[64][72];  // +8 u16 pad
  const int c0 = blockIdx.x * 64;
  const int r0 = blockIdx.y * 64;
  const size_t eoff = (size_t)blockIdx.z * R * C;
  {
    const int c4 = (threadIdx.x & 15) * 4;   // 0..60
    const int rr = threadIdx.x >> 4;         // 0..15
    const float* inp = in + eoff + (size_t)r0 * C + c0;
#pragma unroll
    for (int p = 0; p < 4; ++p) {
      const int r = rr + p * 16;
      const float4 v = *(const float4*)(inp + (size_t)r * C + c4);
      tile[r][c4 + 0] = f2bf(v.x); tile[r][c4 + 1] = f2bf(v.y);
      tile[r][c4 + 2] = f2bf(v.z); tile[r][c4 + 3] = f2bf(v.w);
    }
  }
  __syncthreads();
  {
    u16* op = out + eoff + (size_t)c0 * R + r0;
#pragma unroll
    for (int p = 0; p < 2; ++p) {
      const int c = (threadIdx.x >> 3) + p * 32;
      const int rg = (threadIdx.x & 7) * 8;
      short8 o;
#pragma unroll
      for (int j = 0; j < 8; ++j) o[j] = (short)tile[rg + j][c];
      *(short8*)(op + (size_t)c * R + rg) = o;
    }
  }
}

// ---------------- router ----------------
__global__ void router_kernel(const float* __restrict__ x, const float* __restrict__ Wr,
                              const float* __restrict__ br, int* __restrict__ tki,
                              float* __restrict__ tkw, int* __restrict__ counts,
                              float* __restrict__ zsum) {
  const int wave = threadIdx.x >> 6;
  const int lane = threadIdx.x & 63;
  const int t = blockIdx.x * 4 + wave;
  const float* xr = x + (size_t)t * H_DIM;
  float acc[8];
#pragma unroll
  for (int e = 0; e < 8; ++e) acc[e] = 0.0f;
#pragma unroll
  for (int j = 0; j < 16; ++j) {
    const int hh = j * 64 + lane;
    const float xv = xr[hh];
    const float4 w0 = *(const float4*)(Wr + (size_t)hh * 8);
    const float4 w1 = *(const float4*)(Wr + (size_t)hh * 8 + 4);
    acc[0] += xv * w0.x; acc[1] += xv * w0.y; acc[2] += xv * w0.z; acc[3] += xv * w0.w;
    acc[4] += xv * w1.x; acc[5] += xv * w1.y; acc[6] += xv * w1.z; acc[7] += xv * w1.w;
  }
#pragma unroll
  for (int e = 0; e < 8; ++e) {
    float v = acc[e];
#pragma unroll
    for (int s = 32; s > 0; s >>= 1) v += __shfl_xor(v, s);
    acc[e] = v;
  }
  if (lane == 0) {
    float l[8];
#pragma unroll
    for (int e = 0; e < 8; ++e) l[e] = acc[e] + br[e];
    float mx = l[0];
#pragma unroll
    for (int e = 1; e < 8; ++e) mx = fmaxf(mx, l[e]);
    float p[8], s = 0.0f;
#pragma unroll
    for (int e = 0; e < 8; ++e) { p[e] = __expf(l[e] - mx); s += p[e]; }
    int i0 = 0;
#pragma unroll
    for (int e = 1; e < 8; ++e) if (p[e] > p[i0]) i0 = e;
    int i1 = (i0 == 0) ? 1 : 0;
#pragma unroll
    for (int e = 0; e < 8; ++e) if (e != i1 && e != i0 && p[e] > p[i1]) i1 = e;
    const float ws = p[i0] + p[i1];
    tki[2 * t] = i0; tki[2 * t + 1] = i1;
    tkw[2 * t] = p[i0] / ws; tkw[2 * t + 1] = p[i1] / ws;
    atomicAdd(&counts[i0], 1);
    atomicAdd(&counts[i1], 1);
    atomicAdd(zsum, mx + logf(s));
  }
}

__global__ void prefix_kernel(const int* __restrict__ counts, int* __restrict__ offs) {
  if (threadIdx.x == 0) {
    int a = 0;
#pragma unroll
    for (int e = 0; e < 8; ++e) { offs[e] = a; a += counts[e]; }
  }
}

__global__ void scatter_kernel(const int* __restrict__ tki, const float* __restrict__ tkw,
                               const int* __restrict__ offs, int* __restrict__ cursor,
                               int* __restrict__ perm, float* __restrict__ pw) {
  const int t = blockIdx.x * 256 + threadIdx.x;
#pragma unroll
  for (int k = 0; k < 2; ++k) {
    const int e = tki[2 * t + k];
    const int p = atomicAdd(&cursor[e], 1);
    perm[offs[e] + p] = t;
    pw[offs[e] + p] = tkw[2 * t + k];
  }
}

// ---------------- grouped GEMMs (m97 structure: 128x128 tile, BK=32) ----------------

// h[slot][F] = gelu( xb[perm[slot]] @ W1t[e]^T + b1[e] )  (bf16 out)
__global__ __launch_bounds__(256, 4) void gemm1_kernel(
    const u16* __restrict__ xb, const u16* __restrict__ w1t,
    const float* __restrict__ b1, const int* __restrict__ perm,
    const int* __restrict__ cnts, const int* __restrict__ offs,
    u16* __restrict__ hbuf) {
  const int e = blockIdx.z;
  const int cnt = cnts[e];
  const int m0 = blockIdx.y * 128;
  if (m0 >= cnt) return;
  const int off = offs[e];
  const int n0 = blockIdx.x * 128;

  __shared__ __align__(16) u16 As[128 * 32];
  __shared__ __align__(16) u16 Bs[128 * 32];

  const int tid = threadIdx.x;
  const int r = tid >> 2;
  const int kc = (tid & 3) * 8;

  int ra0 = m0 + r;       if (ra0 > cnt - 1) ra0 = cnt - 1;
  int ra1 = m0 + r + 64;  if (ra1 > cnt - 1) ra1 = cnt - 1;
  const int tok0 = perm[off + ra0];
  const int tok1 = perm[off + ra1];
  const u16* ap0 = xb + (size_t)tok0 * H_DIM + kc;
  const u16* ap1 = xb + (size_t)tok1 * H_DIM + kc;
  const u16* bp0 = w1t + ((size_t)e * F_DIM + n0 + r) * H_DIM + kc;
  const u16* bp1 = bp0 + (size_t)64 * H_DIM;

  const int wave = tid >> 6;
  const int lane = tid & 63;
  const int wm = (wave >> 1) * 64;
  const int wn = (wave & 1) * 64;
  const int lr = lane & 15;
  const int q = lane >> 4;

  f32x4 acc[4][4];
#pragma unroll
  for (int i = 0; i < 4; ++i)
#pragma unroll
    for (int j = 0; j < 4; ++j) acc[i][j] = (f32x4)0.0f;

  const short8* Afr = (const short8*)As;
  const short8* Bfr = (const short8*)Bs;
  const int a_base = (wm + lr) * 4 + q;  // short8 units: row*4 + q
  const int b_base = (wn + lr) * 4 + q;

  for (int k0 = 0; k0 < H_DIM; k0 += 32) {
    gl_lds16(ap0, &As[tid * 8]);
    gl_lds16(ap1, &As[(tid + 256) * 8]);
    gl_lds16(bp0, &Bs[tid * 8]);
    gl_lds16(bp1, &Bs[(tid + 256) * 8]);
    ap0 += 32; ap1 += 32; bp0 += 32; bp1 += 32;
    __syncthreads();
    short8 a[4], b[4];
#pragma unroll
    for (int i = 0; i < 4; ++i) a[i] = Afr[a_base + i * 64];
#pragma unroll
    for (int j = 0; j < 4; ++j) b[j] = Bfr[b_base + j * 64];
#pragma unroll
    for (int i = 0; i < 4; ++i)
#pragma unroll
      for (int j = 0; j < 4; ++j)
        acc[i][j] = __builtin_amdgcn_mfma_f32_16x16x32_bf16(a[i], b[j], acc[i][j], 0, 0, 0);
    __syncthreads();
  }

#pragma unroll
  for (int i = 0; i < 4; ++i) {
#pragma unroll
    for (int rr = 0; rr < 4; ++rr) {
      const int m = m0 + wm + i * 16 + q * 4 + rr;
      if (m < cnt) {
        u16* hrow = hbuf + (size_t)(off + m) * F_DIM;
#pragma unroll
        for (int j = 0; j < 4; ++j) {
          const int col = n0 + wn + j * 16 + lr;
          const float v = acc[i][j][rr] + b1[e * F_DIM + col];
          const float g = 0.5f * v * (1.0f + erff(v * 0.70710678118654752f));
          hrow[col] = f2bf(g);
        }
      }
    }
  }
}

// out[token] += w * (h[slot] @ W2t[e]^T + b2[e])   -- split-K over 4 chunks
__global__ __launch_bounds__(256, 4) void gemm2_kernel(
    const u16* __restrict__ hbuf, const u16* __restrict__ w2t,
    const float* __restrict__ b2, const int* __restrict__ perm,
    const float* __restrict__ pw, const int* __restrict__ cnts,
    const int* __restrict__ offs, float* __restrict__ out) {
  const int ez = blockIdx.z;
  const int e = ez >> 2;
  const int ks = ez & 3;          // split-K chunk
  const int cnt = cnts[e];
  const int m0 = blockIdx.y * 128;
  if (m0 >= cnt) return;
  const int off = offs[e];
  const int n0 = blockIdx.x * 128;
  const int kbeg = ks * (F_DIM / 4);

  __shared__ __align__(16) u16 As[128 * 32];
  __shared__ __align__(16) u16 Bs[128 * 32];

  const int tid = threadIdx.x;
  const int r = tid >> 2;
  const int kc = (tid & 3) * 8;

  int ra0 = m0 + r;       if (ra0 > cnt - 1) ra0 = cnt - 1;
  int ra1 = m0 + r + 64;  if (ra1 > cnt - 1) ra1 = cnt - 1;
  const u16* ap0 = hbuf + (size_t)(off + ra0) * F_DIM + kbeg + kc;
  const u16* ap1 = hbuf + (size_t)(off + ra1) * F_DIM + kbeg + kc;
  const u16* bp0 = w2t + ((size_t)e * H_DIM + n0 + r) * F_DIM + kbeg + kc;
  const u16* bp1 = bp0 + (size_t)64 * F_DIM;

  const int wave = tid >> 6;
  const int lane = tid & 63;
  const int wm = (wave >> 1) * 64;
  const int wn = (wave & 1) * 64;
  const int lr = lane & 15;
  const int q = lane >> 4;

  f32x4 acc[4][4];
#pragma unroll
  for (int i = 0; i < 4; ++i)
#pragma unroll
    for (int j = 0; j < 4; ++j) acc[i][j] = (f32x4)0.0f;

  const short8* Afr = (const short8*)As;
  const short8* Bfr = (const short8*)Bs;
  const int a_base = (wm + lr) * 4 + q;
  const int b_base = (wn + lr) * 4 + q;

  for (int k0 = 0; k0 < F_DIM / 4; k0 += 32) {
    gl_lds16(ap0, &As[tid * 8]);
    gl_lds16(ap1, &As[(tid + 256) * 8]);
    gl_lds16(bp0, &Bs[tid * 8]);
    gl_lds16(bp1, &Bs[(tid + 256) * 8]);
    ap0 += 32; ap1 += 32; bp0 += 32; bp1 += 32;
    __syncthreads();
    short8 a[4], b[4];
#pragma unroll
    for (int i = 0; i < 4; ++i) a[i] = Afr[a_base + i * 64];
#pragma unroll
    for (int j = 0; j < 4; ++j) b[j] = Bfr[b_base + j * 64];
#pragma unroll
    for (int i = 0; i < 4; ++i)
#pragma unroll
      for (int j = 0; j < 4; ++j)
        acc[i][j] = __builtin_amdgcn_mfma_f32_16x16x32_bf16(a[i], b[j], acc[i][j], 0, 0, 0);
    __syncthreads();
  }

#pragma unroll
  for (int i = 0; i < 4; ++i) {
#pragma unroll
    for (int rr = 0; rr < 4; ++rr) {
      const int m = m0 + wm + i * 16 + q * 4 + rr;
      if (m < cnt) {
        const int slot = off + m;
        const int token = perm[slot];
        const float w = pw[slot];
        float* orow = out + (size_t)token * H_DIM;
#pragma unroll
        for (int j = 0; j < 4; ++j) {
          const int col = n0 + wn + j * 16 + lr;
          float y = acc[i][j][rr];
          if (ks == 0) y += b2[e * H_DIM + col];
          atomicAdd(&orow[col], w * y);
        }
      }
    }
  }
}

__global__ void loss_kernel(const int* __restrict__ counts, const float* __restrict__ zsum,
                            float* __restrict__ out_loss) {
  if (threadIdx.x == 0 && blockIdx.x == 0) {
    float aux = 0.0f;
#pragma unroll
    for (int e = 0; e < 8; ++e) {
      const float d = (float)counts[e] / (float)NASSIGN - 0.125f;
      aux += d * d;
    }
    aux *= (1.0f / 8.0f);
    const float z = zsum[0] / (float)T_TOK;
    out_loss[0] = 0.01f * aux + 0.001f * z;
  }
}

// ---------------- launch ----------------

extern "C" void kernel_launch(void* const* d_in, const int* in_sizes, int n_in,
                              void* d_out, int out_size, void* d_ws, size_t ws_size,
                              hipStream_t stream) {
  const float* x  = (const float*)d_in[0];
  const float* Wr = (const float*)d_in[1];
  const float* br = (const float*)d_in[2];
  const float* W1 = (const float*)d_in[3];
  const float* b1 = (const float*)d_in[4];
  const float* W2 = (const float*)d_in[5];
  const float* b2 = (const float*)d_in[6];
  float* out = (float*)d_out;

  // workspace layout (~210 MB)
  char* ws = (char*)d_ws;
  u16* xb    = (u16*)(ws);                          // 8 MB
  u16* w1t   = (u16*)(ws + 8388608ull);             // 64 MB  [E][F][H] bf16
  u16* w2t   = (u16*)(ws + 75497472ull);            // 64 MB  [E][H][F] bf16
  u16* hbuf  = (u16*)(ws + 142606336ull);           // 64 MB  [8192][F] bf16
  int*   tki    = (int*)(ws + 209715200ull);
  float* tkw    = (float*)(ws + 209747968ull);
  int*   perm   = (int*)(ws + 209780736ull);
  float* pw     = (float*)(ws + 209813504ull);
  int*   counts = (int*)(ws + 209846272ull);        // counts[8], offs[8], cursor[8], zsum
  int*   offs   = counts + 8;
  int*   cursor = counts + 16;
  float* zsum   = (float*)(counts + 24);

  hipMemsetAsync(out, 0, (size_t)out_size * sizeof(float), stream);
  hipMemsetAsync(counts, 0, 128, stream);

  cvt_x_kernel<<<2048, 256, 0, stream>>>(x, xb);
  // W1 [E][H][F] -> w1t [E][F][H]:  R=H, C=F
  transpose_cvt_kernel<<<dim3(F_DIM / 64, H_DIM / 64, E_EXP), 256, 0, stream>>>(W1, w1t, H_DIM, F_DIM);
  // W2 [E][F][H] -> w2t [E][H][F]:  R=F, C=H
  transpose_cvt_kernel<<<dim3(H_DIM / 64, F_DIM / 64, E_EXP), 256, 0, stream>>>(W2, w2t, F_DIM, H_DIM);
  router_kernel<<<T_TOK / 4, 256, 0, stream>>>(x, Wr, br, tki, tkw, counts, zsum);
  prefix_kernel<<<1, 64, 0, stream>>>(counts, offs);
  scatter_kernel<<<T_TOK / 256, 256, 0, stream>>>(tki, tkw, offs, cursor, perm, pw);
  gemm1_kernel<<<dim3(F_DIM / 128, T_TOK / 128, E_EXP), 256, 0, stream>>>(
      xb, w1t, b1, perm, counts, offs, hbuf);
  gemm2_kernel<<<dim3(H_DIM / 128, T_TOK / 128, E_EXP * 4), 256, 0, stream>>>(
      hbuf, w2t, b2, perm, pw, counts, offs, out);
  loss_kernel<<<1, 64, 0, stream>>>(counts, zsum, out + OUT_ELEMS);
}